// Round 3
// baseline (198.872 us; speedup 1.0000x reference)
//
#include <hip/hip_runtime.h>
#include <hip/hip_bf16.h>

typedef __bf16 bf16_t;
typedef bf16_t bf16x8 __attribute__((ext_vector_type(8)));
typedef bf16_t bf16x4 __attribute__((ext_vector_type(4)));
typedef float f32x4 __attribute__((ext_vector_type(4)));

#define SEQ    2048
#define DHEAD  64
#define DMODEL 1024
#define KVB    64
#define BHN    64   // B*H
#define LOG2E  1.4426950408889634f

__device__ __forceinline__ f32x4 mfma16(bf16x8 a, bf16x8 b, f32x4 c) {
  return __builtin_amdgcn_mfma_f32_16x16x32_bf16(a, b, c, 0, 0, 0);
}

// async global->LDS, 16B per lane. dest must be wave-uniform base (HW adds lane*16).
__device__ __forceinline__ void gload16(void* l, const void* g) {
  __builtin_amdgcn_global_load_lds(
      (const __attribute__((address_space(1))) unsigned int*)g,
      (__attribute__((address_space(3))) unsigned int*)l,
      16, 0, 0);
}

// ---------------------------------------------------------------------------
// Kernel 1: per-head QKV projection. x [B,S,D] fp32 ->
//   Qw [bh][s][64] bf16 (pre-scaled by log2e/8), Kw [bh][s][64], VTw [bh][64][s].
// grid (8, 64), 256 thr. All outputs stored as bf16x4 vector stores:
//   Q/K use swapped-operand MFMA (D row=e) -> 4 consecutive e per thread;
//   V uses normal orientation (D row=s)    -> 4 consecutive s per thread (VT).
// ---------------------------------------------------------------------------
__global__ __launch_bounds__(256) void qkv_kernel(
    const float* __restrict__ x,
    const float* __restrict__ Wq, const float* __restrict__ bq,
    const float* __restrict__ Wk, const float* __restrict__ bk,
    const float* __restrict__ Wv, const float* __restrict__ bv,
    bf16_t* __restrict__ Qw, bf16_t* __restrict__ Kw, bf16_t* __restrict__ VTw) {
  __shared__ __align__(16) char x_lds[256 * 128];  // 256 rows x 64 bf16, swizzled
  __shared__ __align__(16) char w_lds[8192];       // WT[e][d] bf16 swizzled

  const int bh = blockIdx.y;
  const int b = bh >> 4, h = bh & 15;
  const int s0 = blockIdx.x * 256;
  const int t = threadIdx.x;
  const int w = t >> 6, lane = t & 63;
  const int lo = lane & 15, g = lane >> 4;

  // stage x head-slice into LDS as bf16, XOR-swizzled 128B rows
#pragma unroll
  for (int p = 0; p < 8; ++p) {
    const int row = p * 32 + (t >> 3);
    const int c = t & 7;
    const float* xp = x + ((size_t)(b * SEQ + s0 + row)) * DMODEL + h * DHEAD + c * 8;
    const float4 f0 = *(const float4*)xp;
    const float4 f1 = *(const float4*)(xp + 4);
    bf16x8 v;
    v[0] = (bf16_t)f0.x; v[1] = (bf16_t)f0.y; v[2] = (bf16_t)f0.z; v[3] = (bf16_t)f0.w;
    v[4] = (bf16_t)f1.x; v[5] = (bf16_t)f1.y; v[6] = (bf16_t)f1.z; v[7] = (bf16_t)f1.w;
    *(bf16x8*)(x_lds + row * 128 + ((c * 16) ^ ((row & 7) << 4))) = v;
  }
  __syncthreads();

  for (int wi = 0; wi < 3; ++wi) {
    const float* Wp = (wi == 0) ? Wq : (wi == 1) ? Wk : Wv;
    const float* Bp = (wi == 0) ? bq : (wi == 1) ? bk : bv;
    bf16_t* Op      = (wi == 0) ? Qw : Kw;

    if (wi > 0) __syncthreads();  // prior wf reads of w_lds done
    // stage WT[e][d] bf16 swizzled (coalesced float4 reads of W[h][d][:])
    {
      const int d = t >> 2, e0 = (t & 3) * 16;
      const float* wp = Wp + (size_t)(h * 64 + d) * 64 + e0;
      const float4 f0 = *(const float4*)(wp);
      const float4 f1 = *(const float4*)(wp + 4);
      const float4 f2 = *(const float4*)(wp + 8);
      const float4 f3 = *(const float4*)(wp + 12);
      float vals[16];
      vals[0] = f0.x; vals[1] = f0.y; vals[2] = f0.z; vals[3] = f0.w;
      vals[4] = f1.x; vals[5] = f1.y; vals[6] = f1.z; vals[7] = f1.w;
      vals[8] = f2.x; vals[9] = f2.y; vals[10] = f2.z; vals[11] = f2.w;
      vals[12] = f3.x; vals[13] = f3.y; vals[14] = f3.z; vals[15] = f3.w;
#pragma unroll
      for (int j = 0; j < 16; ++j) {
        const int e = e0 + j;
        *(bf16_t*)(w_lds + e * 128 + ((2 * d) ^ ((e & 7) << 4))) = (bf16_t)vals[j];
      }
    }
    __syncthreads();

    // W frags: lane (lo,g): e=ct*16+lo, d=ks*32+g*8+i (valid as A or B operand)
    bf16x8 wf[2][4];
#pragma unroll
    for (int ct = 0; ct < 4; ++ct)
#pragma unroll
      for (int ks = 0; ks < 2; ++ks)
        wf[ks][ct] = *(const bf16x8*)(w_lds + (ct * 16 + lo) * 128 +
                                      ((ks * 64 + g * 16) ^ ((lo & 7) << 4)));
    float4 biasv[4];   // Q/K path: bias at e = ct*16 + g*4 + r
    float biass[4];    // V path:   bias at e = ct*16 + lo
    if (wi < 2) {
#pragma unroll
      for (int ct = 0; ct < 4; ++ct)
        biasv[ct] = *(const float4*)(Bp + h * 64 + ct * 16 + g * 4);
    } else {
#pragma unroll
      for (int ct = 0; ct < 4; ++ct) biass[ct] = Bp[h * 64 + ct * 16 + lo];
    }

    const float sc = (wi == 0) ? (0.125f * LOG2E) : 1.0f;
#pragma unroll
    for (int it = 0; it < 4; ++it) {
      const int r0 = it * 64 + w * 16;
      bf16x8 xa[2];
#pragma unroll
      for (int ks = 0; ks < 2; ++ks) {
        const int row = r0 + lo;
        xa[ks] = *(const bf16x8*)(x_lds + row * 128 +
                                  ((ks * 64 + g * 16) ^ ((row & 7) << 4)));
      }
      if (wi < 2) {
        // swapped: D[row=e][col=s]; thread: s = s0+r0+lo, e = ct*16+g*4+r
#pragma unroll
        for (int ct = 0; ct < 4; ++ct) {
          f32x4 a = (f32x4){0.f, 0.f, 0.f, 0.f};
          a = mfma16(wf[0][ct], xa[0], a);
          a = mfma16(wf[1][ct], xa[1], a);
          bf16x4 pk;
#pragma unroll
          for (int r = 0; r < 4; ++r)
            pk[r] = (bf16_t)((a[r] + ((const float*)&biasv[ct])[r]) * sc);
          *(bf16x4*)(Op + ((size_t)bh * SEQ + s0 + r0 + lo) * DHEAD + ct * 16 + g * 4) = pk;
        }
      } else {
        // normal: D[row=s][col=e]; thread: e = ct*16+lo, s = s0+r0+g*4+r -> VT store
#pragma unroll
        for (int ct = 0; ct < 4; ++ct) {
          f32x4 a = (f32x4){0.f, 0.f, 0.f, 0.f};
          a = mfma16(xa[0], wf[0][ct], a);
          a = mfma16(xa[1], wf[1][ct], a);
          bf16x4 pk;
#pragma unroll
          for (int r = 0; r < 4; ++r) pk[r] = (bf16_t)(a[r] + biass[ct]);
          *(bf16x4*)(VTw + ((size_t)bh * DHEAD + ct * 16 + lo) * SEQ + s0 + r0 + g * 4) = pk;
        }
      }
    }
  }
}

// ---------------------------------------------------------------------------
// Kernel 2: causal flash attention. QBLK=64 (16 q/wave), 4 waves, KVB=64.
// 1024 blocks = 4/CU (LDS 40960B), pairs (p, 31-p) -> uniform 33 kv-steps.
// Double-buffered gload_lds staging, bf16 P in LDS, defer-max, exp2.
// ---------------------------------------------------------------------------
__global__ __launch_bounds__(256, 4) void attn_kernel(
    const bf16_t* __restrict__ Qw, const bf16_t* __restrict__ Kw,
    const bf16_t* __restrict__ VTw, float* __restrict__ Out) {
  __shared__ __align__(16) char stage_lds[2][16384];  // [buf]: K 8KB | VT 8KB
  __shared__ __align__(16) char p_lds[4][2048];       // per-wave P[16 q][64 kv] bf16 swizzled

  const int f = blockIdx.x;
  const int bh = (f & 7) * 8 + ((f >> 3) & 7);  // cluster 8 bh per XCD
  const int pair = f >> 6;                      // 0..15
  const int b = bh >> 4, h = bh & 15;

  const int t = threadIdx.x;
  const int w = t >> 6, lane = t & 63;
  const int lo = lane & 15, g = lane >> 4;
  char* pbase = &p_lds[w][0];

  const int strow = w * 8 + (lane >> 3);
  const int scol = ((lane & 7) * 16) ^ ((lane >> 3) << 4);
  const char* Kbase = (const char*)(Kw + (size_t)bh * SEQ * DHEAD);
  const char* Vbase = (const char*)(VTw + (size_t)bh * DHEAD * SEQ);
  const bf16_t* Qb = Qw + (size_t)bh * SEQ * DHEAD;
  const int swz = (lo & 7) << 4;

  for (int half = 0; half < 2; ++half) {
    const int qt = half ? (31 - pair) : pair;
    const int q0 = qt * 64;
    const int qw0 = q0 + w * 16;
    const int kts = qt + 1;

    // Q frags: lane holds q = qw0+lo, d = ks*32+g*8..+7 (pre-scaled by log2e/8)
    bf16x8 qf[2];
    {
      const bf16_t* qp = Qb + (size_t)(qw0 + lo) * DHEAD + g * 8;
      qf[0] = *(const bf16x8*)(qp);
      qf[1] = *(const bf16x8*)(qp + 32);
    }
    float m_run = -1e30f, l_run = 0.f;
    f32x4 oacc[4];
#pragma unroll
    for (int dt = 0; dt < 4; ++dt) oacc[dt] = (f32x4){0.f, 0.f, 0.f, 0.f};

    __syncthreads();  // all prior reads of buf0 done before restaging
    {
      char* db = &stage_lds[0][0];
#pragma unroll
      for (int p = 0; p < 2; ++p) {
        gload16(db + p * 4096 + w * 1024,
                Kbase + (size_t)(p * 32 + strow) * 128 + scol);
        gload16(db + 8192 + p * 4096 + w * 1024,
                Vbase + (size_t)(p * 32 + strow) * 4096 + scol);
      }
    }
    int cur = 0;
    for (int kt = 0; kt < kts; ++kt) {
      const int kv0 = kt * KVB;
      __syncthreads();  // implicit vmcnt(0): tile kt landed; prior reads of buf^1 done
      if (kt + 1 < kts) {
        const int nk = kv0 + KVB;
        char* db = &stage_lds[cur ^ 1][0];
#pragma unroll
        for (int p = 0; p < 2; ++p) {
          gload16(db + p * 4096 + w * 1024,
                  Kbase + (size_t)(nk + p * 32 + strow) * 128 + scol);
          gload16(db + 8192 + p * 4096 + w * 1024,
                  Vbase + (size_t)(p * 32 + strow) * 4096 + (size_t)nk * 2 + scol);
        }
      }
      const char* kb = &stage_lds[cur][0];
      const char* vb = kb + 8192;

      // K frags + QK^T (swapped): S^T[kv][q], q=lo, kv=ct*16+g*4+r
      bf16x8 kf[2][4];
#pragma unroll
      for (int ks = 0; ks < 2; ++ks)
#pragma unroll
        for (int ct = 0; ct < 4; ++ct)
          kf[ks][ct] = *(const bf16x8*)(kb + (ct * 16 + lo) * 128 +
                                        ((ks * 64 + g * 16) ^ swz));
      f32x4 sa[4];
      __builtin_amdgcn_s_setprio(1);
#pragma unroll
      for (int ct = 0; ct < 4; ++ct) {
        f32x4 a = (f32x4){0.f, 0.f, 0.f, 0.f};
        a = mfma16(kf[0][ct], qf[0], a);
        a = mfma16(kf[1][ct], qf[1], a);
        sa[ct] = a;
      }
      __builtin_amdgcn_s_setprio(0);

      // softmax in log2 domain (Q pre-scaled by log2e/8)
      if (kt == qt) {  // diagonal tile: causal mask
        const int q = qw0 + lo;
#pragma unroll
        for (int ct = 0; ct < 4; ++ct)
#pragma unroll
          for (int r = 0; r < 4; ++r) {
            const int kv = kv0 + ct * 16 + g * 4 + r;
            if (kv > q) sa[ct][r] = -1e30f;
          }
      }
      float mt = -1e30f;
#pragma unroll
      for (int ct = 0; ct < 4; ++ct)
        mt = fmaxf(mt, fmaxf(fmaxf(sa[ct][0], sa[ct][1]),
                             fmaxf(sa[ct][2], sa[ct][3])));
      mt = fmaxf(mt, __shfl_xor(mt, 16));
      mt = fmaxf(mt, __shfl_xor(mt, 32));
      if (__any(mt > m_run + 8.f)) {  // defer-max rescale
        const float mn = fmaxf(m_run, mt);
        const float rs = exp2f(m_run - mn);
        l_run *= rs;
        m_run = mn;
#pragma unroll
        for (int r = 0; r < 4; ++r) {
          const float fr = __shfl(rs, g * 4 + r);
#pragma unroll
          for (int dt = 0; dt < 4; ++dt) oacc[dt][r] *= fr;
        }
      }
      float lt = 0.f;
#pragma unroll
      for (int ct = 0; ct < 4; ++ct) {
        bf16x4 pk;
#pragma unroll
        for (int r = 0; r < 4; ++r) {
          const float pv = exp2f(sa[ct][r] - m_run);
          lt += pv;
          pk[r] = (bf16_t)pv;
        }
        *(bf16x4*)(pbase + lo * 128 + ((ct * 32 + g * 8) ^ swz)) = pk;
      }
      lt += __shfl_xor(lt, 16);
      lt += __shfl_xor(lt, 32);
      l_run += lt;

      // V frags + PV
      bf16x8 vf[2][4];
#pragma unroll
      for (int ks = 0; ks < 2; ++ks)
#pragma unroll
        for (int dt = 0; dt < 4; ++dt)
          vf[ks][dt] = *(const bf16x8*)(vb + (dt * 16 + lo) * 128 +
                                        ((ks * 64 + g * 16) ^ swz));
      __builtin_amdgcn_s_setprio(1);
#pragma unroll
      for (int ks = 0; ks < 2; ++ks) {
        const bf16x8 pa = *(const bf16x8*)(pbase + lo * 128 + ((ks * 64 + g * 16) ^ swz));
#pragma unroll
        for (int dt = 0; dt < 4; ++dt)
          oacc[dt] = mfma16(pa, vf[ks][dt], oacc[dt]);
      }
      __builtin_amdgcn_s_setprio(0);
      cur ^= 1;
    }
    // epilogue: O/l -> d_out fp32; O row q = qw0+g*4+r, col d = dt*16+lo
    const float inv = 1.f / l_run;
#pragma unroll
    for (int r = 0; r < 4; ++r) {
      const float fr = __shfl(inv, g * 4 + r);
      const int srow = qw0 + g * 4 + r;
      float* op = Out + ((size_t)b * SEQ + srow) * DMODEL + h * DHEAD;
#pragma unroll
      for (int dt = 0; dt < 4; ++dt) op[dt * 16 + lo] = oacc[dt][r] * fr;
    }
  }
}

// ---------------------------------------------------------------------------
// Kernel 3: residual add + LayerNorm, in-place on d_out. 1 block per row.
// ---------------------------------------------------------------------------
__global__ __launch_bounds__(256) void ln_kernel(
    const float* __restrict__ x, const float* __restrict__ gamma,
    const float* __restrict__ beta, float* __restrict__ out) {
  __shared__ float red[8];
  const int row = blockIdx.x;
  const int t = threadIdx.x;
  float* orow = out + (size_t)row * DMODEL;
  const float* xrow = x + (size_t)row * DMODEL;

  const float4 o = *(const float4*)(orow + t * 4);
  const float4 xv = *(const float4*)(xrow + t * 4);
  float y0 = o.x + xv.x, y1 = o.y + xv.y, y2 = o.z + xv.z, y3 = o.w + xv.w;
  float s = y0 + y1 + y2 + y3;
  float sq = y0 * y0 + y1 * y1 + y2 * y2 + y3 * y3;
#pragma unroll
  for (int m = 1; m < 64; m <<= 1) {
    s += __shfl_xor(s, m);
    sq += __shfl_xor(sq, m);
  }
  const int w = t >> 6;
  if ((t & 63) == 0) { red[w] = s; red[4 + w] = sq; }
  __syncthreads();
  const float S = red[0] + red[1] + red[2] + red[3];
  const float SQ = red[4] + red[5] + red[6] + red[7];
  const float mu = S * (1.f / DMODEL);
  const float var = SQ * (1.f / DMODEL) - mu * mu;
  const float rstd = rsqrtf(var + 1e-5f);
  const float4 gv = *(const float4*)(gamma + t * 4);
  const float4 bv = *(const float4*)(beta + t * 4);
  float4 res;
  res.x = (y0 - mu) * rstd * gv.x + bv.x;
  res.y = (y1 - mu) * rstd * gv.y + bv.y;
  res.z = (y2 - mu) * rstd * gv.z + bv.z;
  res.w = (y3 - mu) * rstd * gv.w + bv.w;
  *(float4*)(orow + t * 4) = res;
}

// ---------------------------------------------------------------------------
extern "C" void kernel_launch(void* const* d_in, const int* in_sizes, int n_in,
                              void* d_out, int out_size, void* d_ws, size_t ws_size,
                              hipStream_t stream) {
  const float* x     = (const float*)d_in[0];
  const float* Wq    = (const float*)d_in[1];
  const float* bq    = (const float*)d_in[2];
  const float* Wk    = (const float*)d_in[3];
  const float* bk    = (const float*)d_in[4];
  const float* Wv    = (const float*)d_in[5];
  const float* bv    = (const float*)d_in[6];
  const float* gamma = (const float*)d_in[7];
  const float* beta  = (const float*)d_in[8];
  float* out = (float*)d_out;

  const size_t per = (size_t)BHN * SEQ * DHEAD;  // 8388608 elems
  bf16_t* Qw  = (bf16_t*)d_ws;
  bf16_t* Kw  = Qw + per;
  bf16_t* VTw = Kw + per;

  qkv_kernel<<<dim3(8, 64), 256, 0, stream>>>(x, Wq, bq, Wk, bk, Wv, bv, Qw, Kw, VTw);
  attn_kernel<<<dim3(1024), 256, 0, stream>>>(Qw, Kw, VTw, out);
  ln_kernel<<<dim3(8192), 256, 0, stream>>>(x, gamma, beta, out);
}